// Round 2
// baseline (2732.585 us; speedup 1.0000x reference)
//
#include <hip/hip_runtime.h>

// ---------------------------------------------------------------------------
// GRU (T=256 steps, B=1024, IN=128, H=256) + per-timestep BatchNorm, MI355X.
// Strategy: batch-partitioned persistent recurrence kernel (64 blocks x 16
// rows), fp16 MFMA 16x16x32 with fp32 accumulation, h-state master in fp32
// registers, weights pre-packed into MFMA B-fragment layout (L2-resident).
// R1->R2: bf16 -> fp16 operands (8x lower rounding error, same MFMA rate);
// bf16 run failed absmax 0.207 vs 0.094 from accumulated recurrence rounding.
// ---------------------------------------------------------------------------

typedef _Float16 half8 __attribute__((ext_vector_type(8)));
typedef float floatx4 __attribute__((ext_vector_type(4)));

#define EPS_BN 1e-5f

// ws layout (bytes):
//   [0,        589824)  wg_pack: 16 waves x 36 tiles x 64 lanes x 16B (f16 frags)
//   [589824,   655360)  wl_pack: 64 tiles x 64 lanes x 16B
//   [655360,   659456)  bias_pack: 256 x float4 (br, bz, b_ih_n, b_hh_n)
//   [659456,   921600)  stats: 256 t x 128 c x {sum, sumsq} fp32 (atomics)
#define WS_WG 0
#define WS_WL 589824
#define WS_BIAS 655360
#define WS_STATS 659456

static __device__ __forceinline__ unsigned short f2h(float f) {
    union { _Float16 h; unsigned short u; } v;
    v.h = (_Float16)f;                      // v_cvt_f16_f32, RNE
    return v.u;
}
static __device__ __forceinline__ half8 as_h8(uint4 v) {
    union { uint4 u; half8 h; } x; x.u = v; return x.h;
}
static __device__ __forceinline__ float sigm(float x) {
    return 1.0f / (1.0f + __expf(-x));
}
static __device__ __forceinline__ float tanh_fast(float x) {
    return 1.0f - 2.0f / (__expf(2.0f * x) + 1.0f);
}

// ---------------------------------------------------------------------------
// Pack kernel: weights fp32 -> fp16 MFMA-B-fragment-linear layout; biases.
// B-frag for 16x16x32: lane l holds B[n = n0 + (l&15)][k = k0 + (l>>4)*8 + j].
// wg tile order per wave w: [g(r,z,n)][kt 0..11]; gate col n = g*256 + w*16 + ...
// K order: k<128 -> W_ih (x), k>=128 -> W_hh (h).
// ---------------------------------------------------------------------------
__global__ void pack_kernel(const float* __restrict__ W_ih, const float* __restrict__ W_hh,
                            const float* __restrict__ W_lin, const float* __restrict__ b_ih,
                            const float* __restrict__ b_hh,
                            uint4* __restrict__ wg, uint4* __restrict__ wl,
                            float4* __restrict__ biasp)
{
    int i = blockIdx.x * 256 + threadIdx.x;
    if (i < 36864) {                       // 576 wg tiles x 64 lanes
        int lane = i & 63, tile = i >> 6;
        int w = tile / 36, rem = tile - w * 36;
        int g = rem / 12, kt = rem - g * 12;
        int n = g * 256 + (w << 4) + (lane & 15);
        int k0 = (kt << 5) + ((lane >> 4) << 3);
        const float* p = (k0 < 128) ? (W_ih + n * 128 + k0)
                                    : (W_hh + n * 256 + (k0 - 128));
        unsigned short h[8];
        #pragma unroll
        for (int j = 0; j < 8; ++j) h[j] = f2h(p[j]);
        uint4 v;
        v.x = (unsigned)h[0] | ((unsigned)h[1] << 16);
        v.y = (unsigned)h[2] | ((unsigned)h[3] << 16);
        v.z = (unsigned)h[4] | ((unsigned)h[5] << 16);
        v.w = (unsigned)h[6] | ((unsigned)h[7] << 16);
        wg[i] = v;
    } else if (i < 40960) {                // 64 wl tiles x 64 lanes
        int i2 = i - 36864;
        int lane = i2 & 63, tile = i2 >> 6;        // tile = nt*8 + kt
        int n = (tile >> 3) * 16 + (lane & 15);    // 0..127
        int k0 = ((tile & 7) << 5) + ((lane >> 4) << 3);
        const float* p = W_lin + n * 256 + k0;
        unsigned short h[8];
        #pragma unroll
        for (int j = 0; j < 8; ++j) h[j] = f2h(p[j]);
        uint4 v;
        v.x = (unsigned)h[0] | ((unsigned)h[1] << 16);
        v.y = (unsigned)h[2] | ((unsigned)h[3] << 16);
        v.z = (unsigned)h[4] | ((unsigned)h[5] << 16);
        v.w = (unsigned)h[6] | ((unsigned)h[7] << 16);
        wl[i2] = v;
    } else if (i < 41216) {
        int cb = i - 40960;                // 0..255
        biasp[cb] = make_float4(b_ih[cb] + b_hh[cb],
                                b_ih[256 + cb] + b_hh[256 + cb],
                                b_ih[512 + cb], b_hh[512 + cb]);
    }
}

// ---------------------------------------------------------------------------
// Recurrence kernel: 64 blocks x 1024 threads (16 waves). Block owns 16 batch
// rows for all 256 timesteps. Wave w owns gate cols [w*16, w*16+16).
// LDS: [x|h] A-fragment buffer, 12 kt-tiles x 64 lanes x 16B = 12 KB.
// ---------------------------------------------------------------------------
__global__ __launch_bounds__(1024) void gru_kernel(
    const float* __restrict__ inputs,
    const float* __restrict__ hidden,
    const uint4* __restrict__ wg,
    const uint4* __restrict__ wl,
    const float4* __restrict__ biasp,
    const float* __restrict__ b_lin,
    float* __restrict__ out,
    float* __restrict__ stats)
{
    __shared__ uint4 lds_xh[12 * 64];

    const int tid = threadIdx.x;
    const int lane = tid & 63;
    const int w = tid >> 6;            // wave 0..15
    const int quad = lane >> 4;        // 0..3 (D rows quad*4+d)
    const int nc = lane & 15;          // col within wave's 16
    const int r0 = blockIdx.x << 4;    // first batch row

    const int c = (w << 4) + nc;       // gate col group 0..255
    const float4 bias = biasp[c];
    const uint4* wgw = wg + w * 36 * 64;

    // fp32 master hidden state: rows quad*4+d, col c
    float hreg[4];
    #pragma unroll
    for (int d = 0; d < 4; ++d)
        hreg[d] = hidden[(r0 + (quad << 2) + d) * 256 + c];

    // preload W_lin fragments + bias (waves 0..7 do the y-GEMM)
    half8 wlB[8];
    float blc = 0.0f;
    if (w < 8) {
        blc = b_lin[(w << 4) + nc];
        #pragma unroll
        for (int kt = 0; kt < 8; ++kt)
            wlB[kt] = as_h8(wl[(w * 8 + kt) * 64 + lane]);
    }

    // fragment-write addressing: value at A[m][k]: kt=k>>5, k'=k&31,
    // frag lane = (k'>>3)*16 + m, j = k'&7; ushort index = (kt*64+lane_f)*8 + j.
    unsigned short* lds_u16 = (unsigned short*)lds_xh;
    const int kp = ((w & 1) << 4) + nc;                 // k' within tile
    const int kf_h = 4 + (w >> 1);                      // h occupies kt 4..11
    const int hfrag_base = ((kf_h * 64 + ((kp >> 3) << 4) + (quad << 2)) << 3) + (kp & 7);
    const int kf_x = w >> 1;                            // x occupies kt 0..3 (waves<8)
    const int xfrag_base = ((kf_x * 64 + ((kp >> 3) << 4) + (quad << 2)) << 3) + (kp & 7);

    // init h-fragment (fp16 copy of hreg)
    #pragma unroll
    for (int d = 0; d < 4; ++d)
        lds_u16[hfrag_base + (d << 3)] = f2h(hreg[d]);

    // init x-fragment from inputs [1024,128] fp32
    {
        int kt = tid >> 8, lf = (tid >> 2) & 63, jg = tid & 3;
        int m = lf & 15, k0 = (kt << 5) + ((lf >> 4) << 3) + (jg << 1);
        const float* p = inputs + (r0 + m) * 128 + k0;
        unsigned pk = (unsigned)f2h(p[0]) | ((unsigned)f2h(p[1]) << 16);
        ((unsigned*)lds_xh)[((kt << 6) + lf) * 4 + jg] = pk;
    }
    __syncthreads();

    for (int t = 0; t < 256; ++t) {
        // ---- P1: gate GEMMs. acc_r/acc_z over K=384; n-gate split: ain (x part,
        //      kt 0..3), ahn (h part, kt 4..11) because n = tanh(i_n + r*h_n).
        floatx4 ar = {0.f, 0.f, 0.f, 0.f};
        floatx4 az = {0.f, 0.f, 0.f, 0.f};
        floatx4 ain = {0.f, 0.f, 0.f, 0.f};
        floatx4 ahn = {0.f, 0.f, 0.f, 0.f};
        #pragma unroll
        for (int kt = 0; kt < 12; ++kt) {
            half8 A  = as_h8(lds_xh[(kt << 6) + lane]);
            half8 Br = as_h8(wgw[kt * 64 + lane]);
            half8 Bz = as_h8(wgw[(12 + kt) * 64 + lane]);
            half8 Bn = as_h8(wgw[(24 + kt) * 64 + lane]);
            ar = __builtin_amdgcn_mfma_f32_16x16x32_f16(A, Br, ar, 0, 0, 0);
            az = __builtin_amdgcn_mfma_f32_16x16x32_f16(A, Bz, az, 0, 0, 0);
            if (kt < 4)
                ain = __builtin_amdgcn_mfma_f32_16x16x32_f16(A, Bn, ain, 0, 0, 0);
            else
                ahn = __builtin_amdgcn_mfma_f32_16x16x32_f16(A, Bn, ahn, 0, 0, 0);
        }
        __syncthreads();   // all A-frag reads done before anyone rewrites frags

        // ---- P2: elementwise GRU update (fp32), refresh h master + h-frag
        #pragma unroll
        for (int d = 0; d < 4; ++d) {
            float rr = sigm(ar[d] + bias.x);
            float zz = sigm(az[d] + bias.y);
            float nn = tanh_fast(ain[d] + bias.z + rr * (ahn[d] + bias.w));
            float hnew = (1.0f - zz) * nn + zz * hreg[d];
            hreg[d] = hnew;
            lds_u16[hfrag_base + (d << 3)] = f2h(hnew);
        }
        __syncthreads();   // h-frag complete before y-GEMM reads it

        // ---- P3: y = h_new @ W_lin^T + b_lin (waves 0..7), write out,
        //      stats partials, and feed y back as next x-fragment.
        if (w < 8) {
            floatx4 ay = {0.f, 0.f, 0.f, 0.f};
            #pragma unroll
            for (int kt = 0; kt < 8; ++kt) {
                half8 A = as_h8(lds_xh[((4 + kt) << 6) + lane]);
                ay = __builtin_amdgcn_mfma_f32_16x16x32_f16(A, wlB[kt], ay, 0, 0, 0);
            }
            float s1 = 0.0f, s2 = 0.0f;
            float* orow = out + ((size_t)t << 17) + (size_t)((r0 + (quad << 2)) << 7)
                          + (w << 4) + nc;
            #pragma unroll
            for (int d = 0; d < 4; ++d) {
                float y = ay[d] + blc;
                orow[d << 7] = y;
                s1 += y; s2 += y * y;
                lds_u16[xfrag_base + (d << 3)] = f2h(y);
            }
            s1 += __shfl_xor(s1, 16); s1 += __shfl_xor(s1, 32);
            s2 += __shfl_xor(s2, 16); s2 += __shfl_xor(s2, 32);
            if (lane < 16) {
                int si = ((t << 7) + (w << 4) + lane) << 1;
                atomicAdd(&stats[si], s1);
                atomicAdd(&stats[si + 1], s2);
            }
        }
        __syncthreads();   // x-frag ready for next step's P1
    }
}

// ---------------------------------------------------------------------------
// Normalize kernel: in-place batchnorm on d_out using accumulated stats.
// grid 1024: block = (t, quarter-of-batch). Biased variance, eps inside sqrt.
// ---------------------------------------------------------------------------
__global__ void norm_kernel(float* __restrict__ out, const float* __restrict__ stats)
{
    __shared__ float smean[128], sscale[128];
    int t = blockIdx.x >> 2, q = blockIdx.x & 3;
    int tid = threadIdx.x;
    if (tid < 128) {
        int si = ((t << 7) + tid) << 1;
        float mean = stats[si] * (1.0f / 1024.0f);
        float var = stats[si + 1] * (1.0f / 1024.0f) - mean * mean;
        smean[tid] = mean;
        sscale[tid] = rsqrtf(var + EPS_BN);
    }
    __syncthreads();
    float4* p = (float4*)(out + ((size_t)t << 17) + ((size_t)q << 15));
    for (int i = tid; i < 8192; i += 256) {      // 256 rows x 32 float4
        int cc = (i & 31) << 2;
        float4 v = p[i];
        v.x = (v.x - smean[cc])     * sscale[cc];
        v.y = (v.y - smean[cc + 1]) * sscale[cc + 1];
        v.z = (v.z - smean[cc + 2]) * sscale[cc + 2];
        v.w = (v.w - smean[cc + 3]) * sscale[cc + 3];
        p[i] = v;
    }
}

extern "C" void kernel_launch(void* const* d_in, const int* in_sizes, int n_in,
                              void* d_out, int out_size, void* d_ws, size_t ws_size,
                              hipStream_t stream) {
    (void)in_sizes; (void)n_in; (void)out_size; (void)ws_size;
    const float* inputs = (const float*)d_in[0];
    const float* hidden = (const float*)d_in[1];
    const float* W_ih   = (const float*)d_in[2];
    const float* b_ih   = (const float*)d_in[3];
    const float* W_hh   = (const float*)d_in[4];
    const float* b_hh   = (const float*)d_in[5];
    const float* W_lin  = (const float*)d_in[6];
    const float* b_lin  = (const float*)d_in[7];
    // d_in[8] = n_frames (256, compile-time constant here)

    char* ws = (char*)d_ws;
    uint4*  wg    = (uint4*)(ws + WS_WG);
    uint4*  wl    = (uint4*)(ws + WS_WL);
    float4* biasp = (float4*)(ws + WS_BIAS);
    float*  stats = (float*)(ws + WS_STATS);

    hipMemsetAsync(stats, 0, 256 * 128 * 2 * sizeof(float), stream);
    pack_kernel<<<161, 256, 0, stream>>>(W_ih, W_hh, W_lin, b_ih, b_hh, wg, wl, biasp);
    gru_kernel<<<64, 1024, 0, stream>>>(inputs, hidden, wg, wl, biasp, b_lin,
                                        (float*)d_out, stats);
    norm_kernel<<<1024, 256, 0, stream>>>((float*)d_out, stats);
}

// Round 3
// 2587.316 us; speedup vs baseline: 1.0561x; 1.0561x over previous
//
#include <hip/hip_runtime.h>

// ---------------------------------------------------------------------------
// GRU (T=256 steps, B=1024, IN=128, H=256) + per-timestep BatchNorm, MI355X.
// Batch-partitioned persistent recurrence: 64 blocks x 16 rows, fp16 MFMA
// 16x16x32 w/ fp32 accum, h-state master in fp32 registers.
// R2->R3: (1) ALL weight B-fragments hoisted to VGPRs (loaded once, not per
// step: R2 re-pulled 576 KB/CU/step through L1<->L2 = the 10 us/step stall);
// (2) double-buffered LDS frag buffer -> 3 barriers/step reduced to 2.
// ---------------------------------------------------------------------------

typedef _Float16 half8 __attribute__((ext_vector_type(8)));
typedef float floatx4 __attribute__((ext_vector_type(4)));

#define EPS_BN 1e-5f

// ws layout (bytes):
//   [0,        589824)  wg_pack: 16 waves x 36 tiles x 64 lanes x 16B (f16 frags)
//   [589824,   655360)  wl_pack: 64 tiles x 64 lanes x 16B
//   [655360,   659456)  bias_pack: 256 x float4 (br, bz, b_ih_n, b_hh_n)
//   [659456,   921600)  stats: 256 t x 128 c x {sum, sumsq} fp32 (atomics)
#define WS_WG 0
#define WS_WL 589824
#define WS_BIAS 655360
#define WS_STATS 659456

static __device__ __forceinline__ unsigned short f2h(float f) {
    union { _Float16 h; unsigned short u; } v;
    v.h = (_Float16)f;                      // v_cvt_f16_f32, RNE
    return v.u;
}
static __device__ __forceinline__ half8 as_h8(uint4 v) {
    union { uint4 u; half8 h; } x; x.u = v; return x.h;
}
static __device__ __forceinline__ float sigm(float x) {
    return 1.0f / (1.0f + __expf(-x));
}
static __device__ __forceinline__ float tanh_fast(float x) {
    return 1.0f - 2.0f / (__expf(2.0f * x) + 1.0f);
}

// ---------------------------------------------------------------------------
// Pack kernel: weights fp32 -> fp16 MFMA-B-fragment-linear layout; biases.
// B-frag for 16x16x32: lane l holds B[n = n0 + (l&15)][k = k0 + (l>>4)*8 + j].
// wg tile order per wave w: [g(r,z,n)][kt 0..11]; gate col n = g*256 + w*16 + ...
// K order: k<128 -> W_ih (x), k>=128 -> W_hh (h).
// ---------------------------------------------------------------------------
__global__ void pack_kernel(const float* __restrict__ W_ih, const float* __restrict__ W_hh,
                            const float* __restrict__ W_lin, const float* __restrict__ b_ih,
                            const float* __restrict__ b_hh,
                            uint4* __restrict__ wg, uint4* __restrict__ wl,
                            float4* __restrict__ biasp)
{
    int i = blockIdx.x * 256 + threadIdx.x;
    if (i < 36864) {                       // 576 wg tiles x 64 lanes
        int lane = i & 63, tile = i >> 6;
        int w = tile / 36, rem = tile - w * 36;
        int g = rem / 12, kt = rem - g * 12;
        int n = g * 256 + (w << 4) + (lane & 15);
        int k0 = (kt << 5) + ((lane >> 4) << 3);
        const float* p = (k0 < 128) ? (W_ih + n * 128 + k0)
                                    : (W_hh + n * 256 + (k0 - 128));
        unsigned short h[8];
        #pragma unroll
        for (int j = 0; j < 8; ++j) h[j] = f2h(p[j]);
        uint4 v;
        v.x = (unsigned)h[0] | ((unsigned)h[1] << 16);
        v.y = (unsigned)h[2] | ((unsigned)h[3] << 16);
        v.z = (unsigned)h[4] | ((unsigned)h[5] << 16);
        v.w = (unsigned)h[6] | ((unsigned)h[7] << 16);
        wg[i] = v;
    } else if (i < 40960) {                // 64 wl tiles x 64 lanes
        int i2 = i - 36864;
        int lane = i2 & 63, tile = i2 >> 6;        // tile = nt*8 + kt
        int n = (tile >> 3) * 16 + (lane & 15);    // 0..127
        int k0 = ((tile & 7) << 5) + ((lane >> 4) << 3);
        const float* p = W_lin + n * 256 + k0;
        unsigned short h[8];
        #pragma unroll
        for (int j = 0; j < 8; ++j) h[j] = f2h(p[j]);
        uint4 v;
        v.x = (unsigned)h[0] | ((unsigned)h[1] << 16);
        v.y = (unsigned)h[2] | ((unsigned)h[3] << 16);
        v.z = (unsigned)h[4] | ((unsigned)h[5] << 16);
        v.w = (unsigned)h[6] | ((unsigned)h[7] << 16);
        wl[i2] = v;
    } else if (i < 41216) {
        int cb = i - 40960;                // 0..255
        biasp[cb] = make_float4(b_ih[cb] + b_hh[cb],
                                b_ih[256 + cb] + b_hh[256 + cb],
                                b_ih[512 + cb], b_hh[512 + cb]);
    }
}

// ---------------------------------------------------------------------------
// Recurrence kernel: 64 blocks x 1024 threads (16 waves). Block owns 16 batch
// rows for all 256 timesteps. Wave w owns gate cols [w*16, w*16+16).
// All weight fragments live in VGPRs (~230 total; 4 waves/SIMD needs <=512).
// LDS: double-buffered [x|h] A-fragment buffer, 2 x 12 x 64 x 16B = 24 KB.
// Barriers/step: 2 (h-frag broadcast, x-frag broadcast) — the irreducible
// data dependencies of the recurrence.
// ---------------------------------------------------------------------------
__global__ __launch_bounds__(1024, 4) void gru_kernel(
    const float* __restrict__ inputs,
    const float* __restrict__ hidden,
    const uint4* __restrict__ wg,
    const uint4* __restrict__ wl,
    const float4* __restrict__ biasp,
    const float* __restrict__ b_lin,
    float* __restrict__ out,
    float* __restrict__ stats)
{
    __shared__ uint4 lds_xh[2 * 12 * 64];

    const int tid = threadIdx.x;
    const int lane = tid & 63;
    const int w = tid >> 6;            // wave 0..15
    const int quad = lane >> 4;        // 0..3 (D rows quad*4+d)
    const int nc = lane & 15;          // col within wave's 16
    const int r0 = blockIdx.x << 4;    // first batch row

    const int c = (w << 4) + nc;       // gate col group 0..255
    const float4 bias = biasp[c];
    const uint4* wgw = wg + w * 36 * 64;

    // ---- hoist ALL weights into registers (once; R2 re-read them per step)
    half8 wgB[36];                     // 144 VGPRs: [g*12 + kt]
    #pragma unroll
    for (int i = 0; i < 36; ++i) wgB[i] = as_h8(wgw[i * 64 + lane]);

    half8 wlB[8];                      // 32 VGPRs (used by waves 0..7)
    float blc = 0.0f;
    if (w < 8) {
        blc = b_lin[(w << 4) + nc];
        #pragma unroll
        for (int kt = 0; kt < 8; ++kt)
            wlB[kt] = as_h8(wl[(w * 8 + kt) * 64 + lane]);
    }

    // fp32 master hidden state: rows quad*4+d, col c
    float hreg[4];
    #pragma unroll
    for (int d = 0; d < 4; ++d)
        hreg[d] = hidden[(r0 + (quad << 2) + d) * 256 + c];

    // fragment-write addressing: value at A[m][k]: kt=k>>5, k'=k&31,
    // frag lane = (k'>>3)*16 + m, j = k'&7; ushort index = (kt*64+lane_f)*8 + j.
    unsigned short* lds_u16 = (unsigned short*)lds_xh;
    const int kp = ((w & 1) << 4) + nc;                 // k' within tile
    const int kf_h = 4 + (w >> 1);                      // h occupies kt 4..11
    const int hfrag_base = ((kf_h * 64 + ((kp >> 3) << 4) + (quad << 2)) << 3) + (kp & 7);
    const int kf_x = w >> 1;                            // x occupies kt 0..3 (waves<8)
    const int xfrag_base = ((kf_x * 64 + ((kp >> 3) << 4) + (quad << 2)) << 3) + (kp & 7);

    // init h-fragment into buffer 0 (fp16 copy of hreg)
    #pragma unroll
    for (int d = 0; d < 4; ++d)
        lds_u16[hfrag_base + (d << 3)] = f2h(hreg[d]);

    // init x-fragment (buffer 0) from inputs [1024,128] fp32
    {
        int kt = tid >> 8, lf = (tid >> 2) & 63, jg = tid & 3;
        int m = lf & 15, k0 = (kt << 5) + ((lf >> 4) << 3) + (jg << 1);
        const float* p = inputs + (r0 + m) * 128 + k0;
        unsigned pk = (unsigned)f2h(p[0]) | ((unsigned)f2h(p[1]) << 16);
        ((unsigned*)lds_xh)[((kt << 6) + lf) * 4 + jg] = pk;
    }
    __syncthreads();

    int po = 0;                        // current buffer offset (uint4 units)
    for (int t = 0; t < 256; ++t) {
        const int qo = po ^ 768;       // next buffer (uint4 units)
        const int qo16 = qo << 3;      // same in ushort units

        // ---- P1: gate GEMMs from buf[p]. acc_r/acc_z over K=384; n-gate
        //      split: ain (x part, kt 0..3), ahn (h part, kt 4..11).
        floatx4 ar = {0.f, 0.f, 0.f, 0.f};
        floatx4 az = {0.f, 0.f, 0.f, 0.f};
        floatx4 ain = {0.f, 0.f, 0.f, 0.f};
        floatx4 ahn = {0.f, 0.f, 0.f, 0.f};
        #pragma unroll
        for (int kt = 0; kt < 12; ++kt) {
            half8 A = as_h8(lds_xh[po + (kt << 6) + lane]);
            ar = __builtin_amdgcn_mfma_f32_16x16x32_f16(A, wgB[kt], ar, 0, 0, 0);
            az = __builtin_amdgcn_mfma_f32_16x16x32_f16(A, wgB[12 + kt], az, 0, 0, 0);
            if (kt < 4)
                ain = __builtin_amdgcn_mfma_f32_16x16x32_f16(A, wgB[24 + kt], ain, 0, 0, 0);
            else
                ahn = __builtin_amdgcn_mfma_f32_16x16x32_f16(A, wgB[24 + kt], ahn, 0, 0, 0);
        }
        // no barrier: P2 writes buf[q], P1 read buf[p] (prev-step barriers
        // already ordered everyone's buf[q]-reads before now)

        // ---- P2: elementwise GRU update (fp32), h-frag -> buf[q]
        #pragma unroll
        for (int d = 0; d < 4; ++d) {
            float rr = sigm(ar[d] + bias.x);
            float zz = sigm(az[d] + bias.y);
            float nn = tanh_fast(ain[d] + bias.z + rr * (ahn[d] + bias.w));
            float hnew = (1.0f - zz) * nn + zz * hreg[d];
            hreg[d] = hnew;
            lds_u16[qo16 + hfrag_base + (d << 3)] = f2h(hnew);
        }
        __syncthreads();   // B1: h-frag(q) complete before y-GEMM reads it

        // ---- P3: y = h_new @ W_lin^T + b_lin (waves 0..7), write out,
        //      stats partials, x-frag(q) = y for next step.
        if (w < 8) {
            floatx4 ay = {0.f, 0.f, 0.f, 0.f};
            #pragma unroll
            for (int kt = 0; kt < 8; ++kt) {
                half8 A = as_h8(lds_xh[qo + ((4 + kt) << 6) + lane]);
                ay = __builtin_amdgcn_mfma_f32_16x16x32_f16(A, wlB[kt], ay, 0, 0, 0);
            }
            float s1 = 0.0f, s2 = 0.0f;
            float* orow = out + ((size_t)t << 17) + (size_t)((r0 + (quad << 2)) << 7)
                          + (w << 4) + nc;
            #pragma unroll
            for (int d = 0; d < 4; ++d) {
                float y = ay[d] + blc;
                orow[d << 7] = y;
                s1 += y; s2 += y * y;
                lds_u16[qo16 + xfrag_base + (d << 3)] = f2h(y);
            }
            s1 += __shfl_xor(s1, 16); s1 += __shfl_xor(s1, 32);
            s2 += __shfl_xor(s2, 16); s2 += __shfl_xor(s2, 32);
            if (lane < 16) {
                int si = ((t << 7) + (w << 4) + lane) << 1;
                atomicAdd(&stats[si], s1);
                atomicAdd(&stats[si + 1], s2);
            }
        }
        __syncthreads();   // B2: x-frag(q) ready for next step's P1
        po = qo;
    }
}

// ---------------------------------------------------------------------------
// Normalize kernel: in-place batchnorm on d_out using accumulated stats.
// grid 1024: block = (t, quarter-of-batch). Biased variance, eps inside sqrt.
// ---------------------------------------------------------------------------
__global__ void norm_kernel(float* __restrict__ out, const float* __restrict__ stats)
{
    __shared__ float smean[128], sscale[128];
    int t = blockIdx.x >> 2, q = blockIdx.x & 3;
    int tid = threadIdx.x;
    if (tid < 128) {
        int si = ((t << 7) + tid) << 1;
        float mean = stats[si] * (1.0f / 1024.0f);
        float var = stats[si + 1] * (1.0f / 1024.0f) - mean * mean;
        smean[tid] = mean;
        sscale[tid] = rsqrtf(var + EPS_BN);
    }
    __syncthreads();
    float4* p = (float4*)(out + ((size_t)t << 17) + ((size_t)q << 15));
    for (int i = tid; i < 8192; i += 256) {      // 256 rows x 32 float4
        int cc = (i & 31) << 2;
        float4 v = p[i];
        v.x = (v.x - smean[cc])     * sscale[cc];
        v.y = (v.y - smean[cc + 1]) * sscale[cc + 1];
        v.z = (v.z - smean[cc + 2]) * sscale[cc + 2];
        v.w = (v.w - smean[cc + 3]) * sscale[cc + 3];
        p[i] = v;
    }
}

extern "C" void kernel_launch(void* const* d_in, const int* in_sizes, int n_in,
                              void* d_out, int out_size, void* d_ws, size_t ws_size,
                              hipStream_t stream) {
    (void)in_sizes; (void)n_in; (void)out_size; (void)ws_size;
    const float* inputs = (const float*)d_in[0];
    const float* hidden = (const float*)d_in[1];
    const float* W_ih   = (const float*)d_in[2];
    const float* b_ih   = (const float*)d_in[3];
    const float* W_hh   = (const float*)d_in[4];
    const float* b_hh   = (const float*)d_in[5];
    const float* W_lin  = (const float*)d_in[6];
    const float* b_lin  = (const float*)d_in[7];
    // d_in[8] = n_frames (256, compile-time constant here)

    char* ws = (char*)d_ws;
    uint4*  wg    = (uint4*)(ws + WS_WG);
    uint4*  wl    = (uint4*)(ws + WS_WL);
    float4* biasp = (float4*)(ws + WS_BIAS);
    float*  stats = (float*)(ws + WS_STATS);

    hipMemsetAsync(stats, 0, 256 * 128 * 2 * sizeof(float), stream);
    pack_kernel<<<161, 256, 0, stream>>>(W_ih, W_hh, W_lin, b_ih, b_hh, wg, wl, biasp);
    gru_kernel<<<64, 1024, 0, stream>>>(inputs, hidden, wg, wl, biasp, b_lin,
                                        (float*)d_out, stats);
    norm_kernel<<<1024, 256, 0, stream>>>((float*)d_out, stats);
}